// Round 4
// baseline (47.866 us; speedup 1.0000x reference)
//
#include <hip/hip_runtime.h>

// BlankEmbedding: out[b,s,:] = sum_{m=0..8} c[m] * emb_table[x[b,s-m], :]
// c[m] depends only on the 8 preblank bits p[1..8]; 256-entry constexpr LUT,
// packed as 8 bytes per entry (c[m] <= C(8,m) <= 70). c[0] == 1 always.
// Each block processes P consecutive positions of one batch row (strip),
// unroll-2 over positions for memory-level parallelism.

constexpr int S_LEN = 4096;
constexpr int D_DIM = 2048;
constexpr int P     = 8;      // positions per block (divides S_LEN)

typedef float f32x4 __attribute__((ext_vector_type(4)));

struct CoefTab { unsigned long long v[256]; };

constexpr CoefTab make_tab() {
    CoefTab t{};
    for (int mask = 0; mask < 256; ++mask) {
        int p[9] = {};
        for (int i = 1; i <= 8; ++i) p[i] = (mask >> (i - 1)) & 1;
        int C[9][9] = {};
        for (int j = 0; j < 9; ++j) C[j][0] = 1;
        for (int k = 1; k <= 8; ++k)
            for (int j = 0; j + k <= 8; ++j)
                for (int m = 8; m >= 1; --m)
                    C[j][m] += p[j + k] * C[j + 1][m - 1];
        unsigned long long pack = 0ULL;
        for (int m = 1; m <= 8; ++m)
            pack |= (unsigned long long)(C[0][m] & 0xff) << ((m - 1) * 8);
        t.v[mask] = pack;
    }
    return t;
}

__device__ __constant__ CoefTab cTab = make_tab();

__global__ __launch_bounds__(256)
void blank_emb_kernel(const int* __restrict__ x,
                      const float* __restrict__ table,
                      float* __restrict__ out) {
    const int base = blockIdx.x * P;             // first flattened b*S+s of strip
    const int s0   = base & (S_LEN - 1);
    const int* __restrict__ xb = x + (base - s0);   // batch row start

    const int d0 = (int)threadIdx.x * 4;
    const int d1 = d0 + 1024;

    #pragma unroll 2
    for (int p = 0; p < P; ++p) {
        const int s = s0 + p;

        // ---- block-uniform scalar phase ----
        int tok[9];
        unsigned bl = 0;
        #pragma unroll
        for (int m = 0; m < 9; ++m) {
            const int t  = s - m;
            const int tv = (t >= 0) ? xb[t] : 2048;   // sentinel: non-blank
            tok[m] = (t >= 0) ? tv : 0;               // coeff provably 0 when t<0
            if (tv < 16) bl |= (1u << m);
        }
        const unsigned valid = (s >= 8) ? 0xffu : ((1u << s) - 1u);
        const unsigned mask  = bl & ~(bl >> 1) & valid;
        const unsigned long long pk = cTab.v[mask];   // packed c[1..8]

        // ---- vector phase: 256 threads x 8 floats = 2048-dim row ----
        const float* __restrict__ row0 = table + (size_t)tok[0] * D_DIM;
        f32x4 a0 = *(const f32x4*)(row0 + d0);
        f32x4 a1 = *(const f32x4*)(row0 + d1);

        if (pk) {                                     // ~94%: pure row copy
            #pragma unroll
            for (int m = 1; m < 9; ++m) {
                const int c = (int)((pk >> ((m - 1) * 8)) & 0xff);
                if (c != 0) {
                    const float fc = (float)c;
                    const float* __restrict__ rm = table + (size_t)tok[m] * D_DIM;
                    a0 += fc * *(const f32x4*)(rm + d0);
                    a1 += fc * *(const f32x4*)(rm + d1);
                }
            }
        }

        float* op = out + (size_t)(base + p) * D_DIM;
        __builtin_nontemporal_store(a0, (f32x4*)(op + d0));
        __builtin_nontemporal_store(a1, (f32x4*)(op + d1));
    }
}

extern "C" void kernel_launch(void* const* d_in, const int* in_sizes, int n_in,
                              void* d_out, int out_size, void* d_ws, size_t ws_size,
                              hipStream_t stream) {
    const int*   x     = (const int*)d_in[0];
    const float* table = (const float*)d_in[1];
    float*       out   = (float*)d_out;

    const int BS = in_sizes[0];                // B * S = 16384
    blank_emb_kernel<<<BS / P, 256, 0, stream>>>(x, table, out);
}

// Round 5
// 35.090 us; speedup vs baseline: 1.3641x; 1.3641x over previous
//
#include <hip/hip_runtime.h>

// BlankEmbedding: out[b,s,:] = sum_{m=0..8} c[m] * emb_table[x[b,s-m], :]
// c[m] from 256-entry constexpr LUT over the 8 preblank bits (verified R2/R3).
// XCD-pinned D-chunking: chunk = blockIdx & 7 -> one XCD per D-chunk under
// round-robin dispatch; per-chunk table slice = 2048 rows x 1 KiB = 2 MiB,
// fits the XCD-private 4 MiB L2 -> gather reads become L2 hits, HBM carries
// only the output write stream (nontemporal, no-allocate).

constexpr int S_LEN = 4096;
constexpr int D_DIM = 2048;
constexpr int NXCD  = 8;
constexpr int CW    = D_DIM / NXCD;   // 256 floats = 1 KiB per chunk
constexpr int PB    = 8;              // positions per block (2 per wave)

typedef float f32x4 __attribute__((ext_vector_type(4)));

struct CoefTab { unsigned long long v[256]; };

constexpr CoefTab make_tab() {
    CoefTab t{};
    for (int mask = 0; mask < 256; ++mask) {
        int p[9] = {};
        for (int i = 1; i <= 8; ++i) p[i] = (mask >> (i - 1)) & 1;
        int C[9][9] = {};
        for (int j = 0; j < 9; ++j) C[j][0] = 1;
        for (int k = 1; k <= 8; ++k)
            for (int j = 0; j + k <= 8; ++j)
                for (int m = 8; m >= 1; --m)
                    C[j][m] += p[j + k] * C[j + 1][m - 1];
        unsigned long long pack = 0ULL;
        for (int m = 1; m <= 8; ++m)
            pack |= (unsigned long long)(C[0][m] & 0xff) << ((m - 1) * 8);
        t.v[mask] = pack;
    }
    return t;
}

__device__ __constant__ CoefTab cTab = make_tab();

__global__ __launch_bounds__(256)
void blank_emb_kernel(const int* __restrict__ x,
                      const float* __restrict__ table,
                      float* __restrict__ out) {
    const int bid  = blockIdx.x;
    const int c    = bid & (NXCD - 1);      // D-chunk; round-robin -> XCD-pinned
    const int g    = bid >> 3;              // position group of PB positions
    const int wave = (int)threadIdx.x >> 6;
    const int lane = (int)threadIdx.x & 63;
    const int dcol = c * CW + lane * 4;     // this wave's 4 floats within D

    #pragma unroll
    for (int pp = 0; pp < 2; ++pp) {
        const int pos = g * PB + wave * 2 + pp;   // flattened b*S + s
        const int s   = pos & (S_LEN - 1);
        const int* __restrict__ xb = x + (pos - s);

        // ---- wave-uniform scalar phase (forced to SGPRs) ----
        int tok[9];
        unsigned bl = 0;
        #pragma unroll
        for (int m = 0; m < 9; ++m) {
            const int t  = s - m;
            const int tv = (t >= 0) ? xb[t] : 2048;   // sentinel: non-blank
            tok[m] = __builtin_amdgcn_readfirstlane((t >= 0) ? tv : 0);
            if (tv < 16) bl |= (1u << m);
        }
        const unsigned valid = (s >= 8) ? 0xffu : ((1u << s) - 1u);
        const unsigned mask  =
            __builtin_amdgcn_readfirstlane(bl & ~(bl >> 1) & valid);
        const unsigned long long pk = cTab.v[mask];   // packed c[1..8]

        // ---- vector phase: one f32x4 per lane, 1 KiB per wave ----
        const float* __restrict__ r0 = table + (size_t)tok[0] * D_DIM + dcol;
        f32x4 a = *(const f32x4*)r0;

        if (pk) {                                     // ~94%: pure row copy
            #pragma unroll
            for (int m = 1; m < 9; ++m) {
                const int cf = (int)((pk >> ((m - 1) * 8)) & 0xff);
                if (cf != 0) {
                    const float fc = (float)cf;
                    const float* __restrict__ rm =
                        table + (size_t)tok[m] * D_DIM + dcol;
                    a += fc * *(const f32x4*)rm;
                }
            }
        }

        __builtin_nontemporal_store(
            a, (f32x4*)(out + (size_t)pos * D_DIM + dcol));
    }
}

extern "C" void kernel_launch(void* const* d_in, const int* in_sizes, int n_in,
                              void* d_out, int out_size, void* d_ws, size_t ws_size,
                              hipStream_t stream) {
    const int*   x     = (const int*)d_in[0];
    const float* table = (const float*)d_in[1];
    float*       out   = (float*)d_out;

    const int BS = in_sizes[0];                      // B * S = 16384
    const int grid = (BS / PB) * NXCD;               // 16384 blocks
    blank_emb_kernel<<<grid, 256, 0, stream>>>(x, table, out);
}